// Round 1
// baseline (522.345 us; speedup 1.0000x reference)
//
#include <hip/hip_runtime.h>

#define NN 100000
#define EE 3200000
#define FIN 128
#define HID 16
#define NC 8

// ---- degree ----
__global__ __launch_bounds__(256) void k_deg_init(float* deg) {
    int i = blockIdx.x * 256 + threadIdx.x;
    if (i < NN) deg[i] = 1.0f;  // self-loop contributes 1
}

__global__ __launch_bounds__(256) void k_deg_acc(const int* __restrict__ col, float* deg) {
    int e = blockIdx.x * 256 + threadIdx.x;
    if (e < EE) atomicAdd(&deg[col[e]], 1.0f);
}

// ---- layer 1 transform: hs1 = (x @ W1) * dinv ; agg1 = hs1 (self-loop init) ----
__global__ __launch_bounds__(256) void k_gemm1(const float* __restrict__ x,
                                               const float* __restrict__ W1,
                                               const float* __restrict__ deg,
                                               float* __restrict__ hs1,
                                               float* __restrict__ agg1) {
    __shared__ float w1s[FIN * HID];   // [k][c] row-major, 8 KB
    __shared__ float xs[64 * 132];     // 64 rows, stride 132 (pad 4) -> 2-way bank alias only
    int t = threadIdx.x;
    int r0 = blockIdx.x * 64;
    for (int i = t; i < FIN * HID; i += 256) w1s[i] = W1[i];
    int maxr = NN - r0; if (maxr > 64) maxr = 64;
    const float4* x4 = reinterpret_cast<const float4*>(x + (size_t)r0 * FIN);
    #pragma unroll
    for (int i = 0; i < 8; ++i) {
        int fi = t + i * 256;          // float4 index in tile, 0..2047
        int f = fi * 4;
        int row = f >> 7, k = f & 127;
        if (row < maxr) {
            float4 v = x4[fi];
            *reinterpret_cast<float4*>(&xs[row * 132 + k]) = v;
        }
    }
    __syncthreads();
    int row = t >> 2;
    int cg = (t & 3) * 4;
    if (row < maxr) {
        float4 acc = {0.f, 0.f, 0.f, 0.f};
        const float* xr = &xs[row * 132];
        #pragma unroll 4
        for (int k = 0; k < FIN; ++k) {
            float xv = xr[k];
            const float4 w = *reinterpret_cast<const float4*>(&w1s[k * HID + cg]);
            acc.x += xv * w.x; acc.y += xv * w.y; acc.z += xv * w.z; acc.w += xv * w.w;
        }
        int r = r0 + row;
        float di = rsqrtf(deg[r]);
        acc.x *= di; acc.y *= di; acc.z *= di; acc.w *= di;
        *reinterpret_cast<float4*>(&hs1[r * HID + cg])  = acc;
        *reinterpret_cast<float4*>(&agg1[r * HID + cg]) = acc;
    }
}

// ---- layer 1 scatter: one thread per (edge, channel) ----
__global__ __launch_bounds__(256) void k_scatter1(const int* __restrict__ row,
                                                  const int* __restrict__ col,
                                                  const float* __restrict__ hs1,
                                                  float* agg1) {
    int idx = blockIdx.x * 256 + threadIdx.x;   // < EE*16 = 51.2M
    int e = idx >> 4, c = idx & 15;
    int s = row[e], d = col[e];
    atomicAdd(&agg1[d * HID + c], hs1[s * HID + c]);
}

// ---- finalize layer1 + transform layer2: h1=relu(agg1*dinv+b1); hs2=(h1@W2)*dinv; agg2=hs2 ----
__global__ __launch_bounds__(256) void k_fin1(const float* __restrict__ agg1,
                                              const float* __restrict__ deg,
                                              const float* __restrict__ W2,
                                              const float* __restrict__ b1,
                                              float* __restrict__ hs2,
                                              float* __restrict__ agg2) {
    __shared__ float w2s[HID * NC];
    __shared__ float b1s[HID];
    int t = threadIdx.x;
    if (t < HID * NC) w2s[t] = W2[t];
    if (t < HID) b1s[t] = b1[t];
    __syncthreads();
    int i = blockIdx.x * 256 + t;
    if (i >= NN) return;
    float di = rsqrtf(deg[i]);
    float h[HID];
    const float4* a4 = reinterpret_cast<const float4*>(agg1 + (size_t)i * HID);
    #pragma unroll
    for (int q = 0; q < 4; ++q) {
        float4 v = a4[q];
        h[q*4+0] = fmaxf(v.x * di + b1s[q*4+0], 0.f);
        h[q*4+1] = fmaxf(v.y * di + b1s[q*4+1], 0.f);
        h[q*4+2] = fmaxf(v.z * di + b1s[q*4+2], 0.f);
        h[q*4+3] = fmaxf(v.w * di + b1s[q*4+3], 0.f);
    }
    float o[NC];
    #pragma unroll
    for (int c = 0; c < NC; ++c) o[c] = 0.f;
    #pragma unroll
    for (int k = 0; k < HID; ++k) {
        float hv = h[k];
        #pragma unroll
        for (int c = 0; c < NC; ++c) o[c] += hv * w2s[k * NC + c];
    }
    float4 v0 = {o[0]*di, o[1]*di, o[2]*di, o[3]*di};
    float4 v1 = {o[4]*di, o[5]*di, o[6]*di, o[7]*di};
    float4* h2 = reinterpret_cast<float4*>(hs2 + (size_t)i * NC);
    float4* a2 = reinterpret_cast<float4*>(agg2 + (size_t)i * NC);
    h2[0] = v0; h2[1] = v1; a2[0] = v0; a2[1] = v1;
}

// ---- layer 2 scatter ----
__global__ __launch_bounds__(256) void k_scatter2(const int* __restrict__ row,
                                                  const int* __restrict__ col,
                                                  const float* __restrict__ hs2,
                                                  float* agg2) {
    int idx = blockIdx.x * 256 + threadIdx.x;   // < EE*8 = 25.6M
    int e = idx >> 3, c = idx & 7;
    int s = row[e], d = col[e];
    atomicAdd(&agg2[d * NC + c], hs2[s * NC + c]);
}

// ---- finalize layer2 + log_softmax ----
__global__ __launch_bounds__(256) void k_fin2(const float* __restrict__ agg2,
                                              const float* __restrict__ deg,
                                              const float* __restrict__ b2,
                                              float* __restrict__ out) {
    __shared__ float b2s[NC];
    int t = threadIdx.x;
    if (t < NC) b2s[t] = b2[t];
    __syncthreads();
    int i = blockIdx.x * 256 + t;
    if (i >= NN) return;
    float di = rsqrtf(deg[i]);
    const float4* a4 = reinterpret_cast<const float4*>(agg2 + (size_t)i * NC);
    float4 u0 = a4[0], u1 = a4[1];
    float v[NC] = {u0.x, u0.y, u0.z, u0.w, u1.x, u1.y, u1.z, u1.w};
    #pragma unroll
    for (int c = 0; c < NC; ++c) v[c] = v[c] * di + b2s[c];
    float m = v[0];
    #pragma unroll
    for (int c = 1; c < NC; ++c) m = fmaxf(m, v[c]);
    float s = 0.f;
    #pragma unroll
    for (int c = 0; c < NC; ++c) s += expf(v[c] - m);
    float ls = logf(s);
    float4 o0 = {v[0]-m-ls, v[1]-m-ls, v[2]-m-ls, v[3]-m-ls};
    float4 o1 = {v[4]-m-ls, v[5]-m-ls, v[6]-m-ls, v[7]-m-ls};
    float4* op = reinterpret_cast<float4*>(out + (size_t)i * NC);
    op[0] = o0; op[1] = o1;
}

extern "C" void kernel_launch(void* const* d_in, const int* in_sizes, int n_in,
                              void* d_out, int out_size, void* d_ws, size_t ws_size,
                              hipStream_t stream) {
    const float* x   = (const float*)d_in[0];
    const int*   ei  = (const int*)d_in[1];     // [2, E]: row then col
    const float* W1  = (const float*)d_in[2];
    const float* b1  = (const float*)d_in[3];
    const float* W2  = (const float*)d_in[4];
    const float* b2  = (const float*)d_in[5];
    float* out = (float*)d_out;

    const int* row = ei;
    const int* col = ei + EE;

    float* ws   = (float*)d_ws;
    float* deg  = ws;                   // N
    float* hs1  = deg  + NN;            // N*16
    float* agg1 = hs1  + (size_t)NN * HID;  // N*16
    float* hs2  = agg1 + (size_t)NN * HID;  // N*8
    float* agg2 = hs2  + (size_t)NN * NC;   // N*8

    const int nb_n = (NN + 255) / 256;          // 391

    k_deg_init<<<nb_n, 256, 0, stream>>>(deg);
    k_deg_acc<<<(EE + 255) / 256, 256, 0, stream>>>(col, deg);
    k_gemm1<<<(NN + 63) / 64, 256, 0, stream>>>(x, W1, deg, hs1, agg1);
    k_scatter1<<<(size_t)EE * HID / 256, 256, 0, stream>>>(row, col, hs1, agg1);
    k_fin1<<<nb_n, 256, 0, stream>>>(agg1, deg, W2, b1, hs2, agg2);
    k_scatter2<<<(size_t)EE * NC / 256, 256, 0, stream>>>(row, col, hs2, agg2);
    k_fin2<<<nb_n, 256, 0, stream>>>(agg2, deg, b2, out);
}